// Round 12
// baseline (37.607 us; speedup 1.0000x reference)
//
#include <hip/hip_runtime.h>
#include <math.h>

// B=32, S=4096, Hd=256.
// scores[b,s] = dot(u[b,s,:], wu_eff) + c[b]; c[b] const over s -> cancels in softmax.
// wu_eff[h] = sum_k v_param[k]*W_attn[k,h]. |score| < ~3 => exp w/o max-subtract is
// exact in f32 (validated R1-R10, absmax ~2e-6).
// Cross-XCD cost model (measured): release writeback ~70ns SERIALIZED (R6), acquire
// fence ~50ns SERIALIZED (R9), same-line RMW ~4.5ns serialized (R3), relaxed agent
// coherent LOADS pipeline fine (R10: 524K in a 22us dispatch).
// R11 bug: tail-detect (old&63)==63 fired at the 22nd arrival (poison base ≡42 mod
// 64) -> sum over ~22/64 partials, absmax 0.125. R12: producers ZERO the counters
// before the release wu-flag (zeroing ordered-before any consumer's increment, which
// happens ~20us later after the streaming pass), so tail is exact old==63. Also:
// all blocks poll their batch counter to 64 and redundantly reduce the partials
// (no inv/flag indirection); partial published via relaxed agent EXCHANGE (RMW is
// performed at the coherence point) + asm s_waitcnt w/ memory clobber (HW wait AND
// compiler ordering) before the counter add.

#define S_LEN 4096
#define HD    256
#define B_N   32
#define NBLK  2048   // 64 blocks per batch
#define RPB   64     // rows per block
#define MAGIC 0x5EED5EEDu

// ws: wu[256] @0 | wuflags 8x(128B) @1024 | cnt 32x(128B) @2048 | part u64[2048] @6144

__global__ void __launch_bounds__(256)
fused_kernel(const float* __restrict__ u, const float* __restrict__ v,
             const float* __restrict__ W, const float* __restrict__ vp,
             float* __restrict__ wu, unsigned* __restrict__ wuflags,
             unsigned* __restrict__ cnt, unsigned long long* __restrict__ part,
             float* __restrict__ w_d, float* __restrict__ attn)
{
    const int t    = threadIdx.x;
    const int wid  = t >> 6;
    const int lane = t & 63;
    const int g    = lane >> 4;
    const int sub  = lane & 15;
    const int b    = blockIdx.x >> 6;          // 64 blocks per batch
    const int row0 = blockIdx.x * RPB;
    const int off0 = sub * 4;

    __shared__ float red8[8][32];
    __shared__ float s_wu[HD];
    __shared__ float e_lds[RPB];
    __shared__ float redw[8];
    __shared__ unsigned s_rank;

    // ---- producers: blocks 0..7 compute wu slice; zero counters; release flag ----
    if (blockIdx.x < 8) {
        // zero 4 of the 32 padded counters (visible before wuflag release)
        if (t < 4)
            __hip_atomic_exchange(&cnt[(blockIdx.x * 4 + t) * 32], 0u,
                                  __ATOMIC_RELAXED, __HIP_MEMORY_SCOPE_AGENT);
        const int hh = t & 31;
        const int kk = t >> 5;
        const int h  = blockIdx.x * 32 + hh;
        float p = 0.f;
#pragma unroll 8
        for (int k = kk * 32; k < kk * 32 + 32; ++k)
            p = fmaf(vp[k], W[k * (2 * HD) + h], p);   // Wu[k,h]
        red8[kk][hh] = p;
        __syncthreads();
        if (kk == 0) {
            float a = 0.f;
#pragma unroll
            for (int j = 0; j < 8; ++j) a += red8[j][hh];
            wu[h] = a;
        }
        __syncthreads();                               // wu stores + cnt zeroing done
        if (t == 0)                                    // release: 8 writebacks total
            __hip_atomic_store(&wuflags[blockIdx.x * 32], MAGIC,
                               __ATOMIC_RELEASE, __HIP_MEMORY_SCOPE_AGENT);
    }

    // ---- prefetch independent data while (possibly) waiting ----
    float4 v4[4];
#pragma unroll
    for (int i = 0; i < 4; ++i)
        v4[i] = *reinterpret_cast<const float4*>(v + b * HD + i * 64 + off0);
    const int sl0 = wid * 16 + g;
    const size_t ub0 = (size_t)(row0 + sl0) * HD;
    float4 u0[4];
#pragma unroll
    for (int i = 0; i < 4; ++i)
        u0[i] = *reinterpret_cast<const float4*>(u + ub0 + i * 64 + off0);

    // ---- wait for wu (relaxed coherent polls, no fence) ----
    if (t == 0) {
        for (;;) {
            unsigned ok = 0;
#pragma unroll
            for (int i = 0; i < 8; ++i)
                ok += (__hip_atomic_load(&wuflags[i * 32], __ATOMIC_RELAXED,
                                         __HIP_MEMORY_SCOPE_AGENT) == MAGIC);
            if (ok == 8) break;
            __builtin_amdgcn_s_sleep(8);
        }
    }
    __syncthreads();

    // ---- read wu coherently (1 relaxed agent load/thread), share via LDS ----
    s_wu[t] = __hip_atomic_load(&wu[t], __ATOMIC_RELAXED, __HIP_MEMORY_SCOPE_AGENT);
    __syncthreads();

    float4 w4[4];
#pragma unroll
    for (int i = 0; i < 4; ++i)
        w4[i] = *reinterpret_cast<const float4*>(&s_wu[i * 64 + off0]);

    // ---- streaming pass: 64 rows, e kept in LDS ----
    float acc_e = 0.f, acc_d = 0.f;
#pragma unroll
    for (int shot = 0; shot < 4; ++shot) {
        const int sl = wid * 16 + shot * 4 + g;          // block-local row 0..63
        const size_t ubase = (size_t)(row0 + sl) * HD;
        float sc = 0.f, dd = 0.f;
#pragma unroll
        for (int i = 0; i < 4; ++i) {
            const float4 u4 = (shot == 0) ? u0[i]
                : *reinterpret_cast<const float4*>(u + ubase + i * 64 + off0);
            sc = fmaf(u4.x, w4[i].x, fmaf(u4.y, w4[i].y, fmaf(u4.z, w4[i].z, fmaf(u4.w, w4[i].w, sc))));
            const float dx = u4.x - v4[i].x, dy = u4.y - v4[i].y,
                        dz = u4.z - v4[i].z, dw = u4.w - v4[i].w;
            dd = fmaf(dx, dx, fmaf(dy, dy, fmaf(dz, dz, fmaf(dw, dw, dd))));
        }
#pragma unroll
        for (int m = 1; m < 16; m <<= 1) {
            sc += __shfl_xor(sc, m);
            dd += __shfl_xor(dd, m);
        }
        const float e = __expf(sc);
        if (sub == 0) e_lds[sl] = e;
        acc_e += e;
        acc_d += e * sqrtf(dd);
    }
#pragma unroll
    for (int m = 16; m < 64; m <<= 1) {
        acc_e += __shfl_xor(acc_e, m);
        acc_d += __shfl_xor(acc_d, m);
    }
    if (lane == 0) { redw[wid] = acc_e; redw[4 + wid] = acc_d; }
    __syncthreads();

    // ---- publish partial (coherence-point RMW), then count arrival ----
    if (t == 0) {
        union { float f[2]; unsigned long long u64; } pk;
        pk.f[0] = redw[0] + redw[1] + redw[2] + redw[3];
        pk.f[1] = redw[4] + redw[5] + redw[6] + redw[7];
        __hip_atomic_exchange(&part[blockIdx.x], pk.u64,
                              __ATOMIC_RELAXED, __HIP_MEMORY_SCOPE_AGENT);
        asm volatile("s_waitcnt vmcnt(0)" ::: "memory");   // performed before counting
        s_rank = __hip_atomic_fetch_add(&cnt[b * 32], 1u,
                              __ATOMIC_RELAXED, __HIP_MEMORY_SCOPE_AGENT);
        // poll batch counter to 64 (relaxed coherent loads)
        while (__hip_atomic_load(&cnt[b * 32], __ATOMIC_RELAXED,
                                 __HIP_MEMORY_SCOPE_AGENT) < 64u)
            __builtin_amdgcn_s_sleep(2);
    }
    __syncthreads();

    // ---- every block: redundant reduce of its batch's 64 partials ----
    union { float f[2]; unsigned long long u64; } pk;
    pk.u64 = __hip_atomic_load(&part[(b << 6) + lane],
                               __ATOMIC_RELAXED, __HIP_MEMORY_SCOPE_AGENT);
    float pe = pk.f[0], pd = pk.f[1];
#pragma unroll
    for (int m = 1; m < 64; m <<= 1) {
        pe += __shfl_xor(pe, m);
        pd += __shfl_xor(pd, m);
    }
    const float inv = 1.f / pe;
    if (t == 0 && s_rank == 63u) w_d[b] = pd * inv;    // exactly one block per batch
    if (t < RPB) attn[row0 + t] = e_lds[t] * inv;      // coalesced 256B/block
}

extern "C" void kernel_launch(void* const* d_in, const int* in_sizes, int n_in,
                              void* d_out, int out_size, void* d_ws, size_t ws_size,
                              hipStream_t stream) {
    const float* u  = (const float*)d_in[0];   // (32, 4096, 256)
    const float* v  = (const float*)d_in[1];   // (32, 256)
    const float* W  = (const float*)d_in[2];   // (256, 512)
    // d_in[3] = b_attn: cancels in softmax, unused.
    const float* vp = (const float*)d_in[4];   // (256,)

    float* out  = (float*)d_out;
    float* w_d  = out;          // 32 floats
    float* attn = out + B_N;    // 32*4096 floats

    char*               ws      = (char*)d_ws;
    float*              wu      = (float*)ws;                    // 256 f32
    unsigned*           wuflags = (unsigned*)(ws + 1024);        // 8, 128B apart
    unsigned*           cnt     = (unsigned*)(ws + 2048);        // 32, 128B apart
    unsigned long long* part    = (unsigned long long*)(ws + 6144); // 2048 u64

    fused_kernel<<<NBLK, 256, 0, stream>>>(u, v, W, vp, wu, wuflags, cnt, part,
                                           w_d, attn);
}

// Round 13
// 28.131 us; speedup vs baseline: 1.3369x; 1.3369x over previous
//
#include <hip/hip_runtime.h>
#include <math.h>

// B=32, S=4096, Hd=256.
// scores[b,s] = dot(u[b,s,:], wu_eff) + c[b]; c[b] const over s -> cancels in softmax.
// wu_eff[h] = sum_k v_param[k]*W_attn[k,h]. |score| < ~3 => exp w/o max-subtract is
// exact in f32 (validated R1-R12, absmax ~2e-6).
// Cross-XCD cost model (measured): release writeback ~70ns serialized (R6); acquire
// fence ~50ns serialized (R9); same-line RMW ~4.5ns serialized (R3); relaxed agent
// coherent LOADS pipeline (R10) but hammering few lines at the coherence point is
// still slower than cached loads; in-kernel per-batch barrier costs +10us (R12).
// R13 = R10 structure (best correct: 27.97us) with ONE change: after the coherent
// wuflags poll, wu is read with PLAIN cached float4 loads. Safe because kernel-start
// acquire invalidates L2; no wave touches wu before its poll succeeds, so the first
// access on each XCD misses to L3, which the producers' release flag-store already
// made fresh (release = producer-L2 writeback BEFORE flag visibility).

#define S_LEN 4096
#define HD    256
#define B_N   32
#define NBLK  2048   // 64 blocks per batch
#define RPB   64     // rows per block
#define MAGIC 0x5EED5EEDu

// ws: wu[256] @0 (1KB) | wuflags 8x(128B) @1024 (1KB)
//     part_e[2048] @2048 (8KB) | part_d[2048] @10240 (8KB) | e_b[131072] @18432 (512KB)

__global__ void __launch_bounds__(256)
score_kernel(const float* __restrict__ u, const float* __restrict__ v,
             const float* __restrict__ W, const float* __restrict__ vp,
             float* __restrict__ wu, unsigned* __restrict__ wuflags,
             float* __restrict__ e_b,
             float* __restrict__ part_e, float* __restrict__ part_d)
{
    const int t    = threadIdx.x;
    const int wid  = t >> 6;
    const int lane = t & 63;
    const int g    = lane >> 4;
    const int sub  = lane & 15;
    const int b    = blockIdx.x >> 6;          // 64 blocks per batch
    const int row0 = blockIdx.x * RPB;
    const int off0 = sub * 4;

    __shared__ float red8[8][32];

    // ---- producers: blocks 0..7 compute wu slice h in [bid*32, bid*32+32) ----
    if (blockIdx.x < 8) {
        const int hh = t & 31;
        const int kk = t >> 5;
        const int h  = blockIdx.x * 32 + hh;
        float p = 0.f;
#pragma unroll 8
        for (int k = kk * 32; k < kk * 32 + 32; ++k)
            p = fmaf(vp[k], W[k * (2 * HD) + h], p);   // Wu[k,h]
        red8[kk][hh] = p;
        __syncthreads();
        if (kk == 0) {
            float a = 0.f;
#pragma unroll
            for (int j = 0; j < 8; ++j) a += red8[j][hh];
            wu[h] = a;                                  // plain store
        }
        __syncthreads();                                // stores issued+waited
        if (t == 0)                                     // release: writeback (8 total)
            __hip_atomic_store(&wuflags[blockIdx.x * 32], MAGIC,
                               __ATOMIC_RELEASE, __HIP_MEMORY_SCOPE_AGENT);
    }

    // ---- prefetch independent data while (possibly) waiting ----
    float4 v4[4];
#pragma unroll
    for (int i = 0; i < 4; ++i)
        v4[i] = *reinterpret_cast<const float4*>(v + b * HD + i * 64 + off0);
    const int sl0 = wid * 16 + g;                       // shot-0 local row
    const size_t ub0 = (size_t)(row0 + sl0) * HD;
    float4 u0[4];
#pragma unroll
    for (int i = 0; i < 4; ++i)
        u0[i] = *reinterpret_cast<const float4*>(u + ub0 + i * 64 + off0);

    // ---- wait for all 8 wu slices (relaxed coherent polls, no fence) ----
    if (t == 0) {
        for (;;) {
            unsigned ok = 0;
#pragma unroll
            for (int i = 0; i < 8; ++i)
                ok += (__hip_atomic_load(&wuflags[i * 32], __ATOMIC_RELAXED,
                                         __HIP_MEMORY_SCOPE_AGENT) == MAGIC);
            if (ok == 8) break;
            __builtin_amdgcn_s_sleep(8);
        }
    }
    __syncthreads();

    // ---- read wu with PLAIN cached loads (fresh via L3; see header comment) ----
    float4 w4[4];
#pragma unroll
    for (int i = 0; i < 4; ++i)
        w4[i] = *reinterpret_cast<const float4*>(wu + i * 64 + off0);

    float acc_e = 0.f, acc_d = 0.f;
#pragma unroll
    for (int shot = 0; shot < 4; ++shot) {
        const int sl = wid * 16 + shot * 4 + g;          // block-local row 0..63
        const size_t ubase = (size_t)(row0 + sl) * HD;
        float sc = 0.f, dd = 0.f;
#pragma unroll
        for (int i = 0; i < 4; ++i) {
            const float4 u4 = (shot == 0) ? u0[i]
                : *reinterpret_cast<const float4*>(u + ubase + i * 64 + off0);
            sc = fmaf(u4.x, w4[i].x, fmaf(u4.y, w4[i].y, fmaf(u4.z, w4[i].z, fmaf(u4.w, w4[i].w, sc))));
            const float dx = u4.x - v4[i].x, dy = u4.y - v4[i].y,
                        dz = u4.z - v4[i].z, dw = u4.w - v4[i].w;
            dd = fmaf(dx, dx, fmaf(dy, dy, fmaf(dz, dz, fmaf(dw, dw, dd))));
        }
#pragma unroll
        for (int m = 1; m < 16; m <<= 1) {
            sc += __shfl_xor(sc, m);
            dd += __shfl_xor(dd, m);
        }
        const float e = __expf(sc);
        if (sub == 0) e_b[row0 + sl] = e;
        acc_e += e;
        acc_d += e * sqrtf(dd);
    }
#pragma unroll
    for (int m = 16; m < 64; m <<= 1) {
        acc_e += __shfl_xor(acc_e, m);
        acc_d += __shfl_xor(acc_d, m);
    }

    __shared__ float redw[8];
    if (lane == 0) { redw[wid] = acc_e; redw[4 + wid] = acc_d; }
    __syncthreads();
    if (t == 0)       part_e[blockIdx.x] = redw[0] + redw[1] + redw[2] + redw[3];
    else if (t == 64) part_d[blockIdx.x] = redw[4] + redw[5] + redw[6] + redw[7];
}

// 128 blocks x 256 threads. b = bid>>2, quarter q = bid&3. Plain loads: fresh via
// dispatch-boundary acquire.
__global__ void finalize_kernel(const float* __restrict__ e_in,
                                const float* __restrict__ part_e, const float* __restrict__ part_d,
                                float* __restrict__ w_d, float* __restrict__ attn) {
    const int t    = threadIdx.x;
    const int b    = blockIdx.x >> 2;
    const int q    = blockIdx.x & 3;
    const int lane = t & 63;

    float pe = part_e[(b << 6) + lane];
    float pd = part_d[(b << 6) + lane];
#pragma unroll
    for (int m = 1; m < 64; m <<= 1) {
        pe += __shfl_xor(pe, m);
        pd += __shfl_xor(pd, m);
    }
    const float inv = 1.f / pe;
    if (q == 0 && t == 0) w_d[b] = pd * inv;

    const int i0 = b * S_LEN + q * 1024 + t * 4;
    const float4 e4 = *reinterpret_cast<const float4*>(e_in + i0);
    float4 a4;
    a4.x = e4.x * inv; a4.y = e4.y * inv; a4.z = e4.z * inv; a4.w = e4.w * inv;
    *reinterpret_cast<float4*>(attn + i0) = a4;
}

extern "C" void kernel_launch(void* const* d_in, const int* in_sizes, int n_in,
                              void* d_out, int out_size, void* d_ws, size_t ws_size,
                              hipStream_t stream) {
    const float* u  = (const float*)d_in[0];   // (32, 4096, 256)
    const float* v  = (const float*)d_in[1];   // (32, 256)
    const float* W  = (const float*)d_in[2];   // (256, 512)
    // d_in[3] = b_attn: cancels in softmax, unused.
    const float* vp = (const float*)d_in[4];   // (256,)

    float* out  = (float*)d_out;
    float* w_d  = out;          // 32 floats
    float* attn = out + B_N;    // 32*4096 floats

    char*     ws      = (char*)d_ws;
    float*    wu      = (float*)ws;               // 256 f32
    unsigned* wuflags = (unsigned*)(ws + 1024);   // 8 flags, 128B apart
    float*    part_e  = (float*)(ws + 2048);      // 2048 f32
    float*    part_d  = (float*)(ws + 10240);     // 2048 f32
    float*    e_b     = (float*)(ws + 18432);     // 131072 f32

    score_kernel<<<NBLK, 256, 0, stream>>>(u, v, W, vp, wu, wuflags, e_b, part_e, part_d);
    finalize_kernel<<<128, 256, 0, stream>>>(e_b, part_e, part_d, w_d, attn);
}

// Round 14
// 27.793 us; speedup vs baseline: 1.3531x; 1.0121x over previous
//
#include <hip/hip_runtime.h>
#include <math.h>

// B=32, S=4096, Hd=256.
// scores[b,s] = dot(u[b,s,:], wu_eff) + c[b]; c[b] const over s -> cancels in softmax.
// wu_eff[h] = sum_k v_param[k]*W_attn[k,h]. |score| < ~3 => exp w/o max-subtract is
// exact in f32 (validated R1-R13, absmax ~2e-6).
// Cross-XCD cost model (measured): release writeback ~70ns serialized (R6); acquire
// fence ~50ns serialized (R9); same-line RMW ~4.5ns serialized (R3); relaxed agent
// coherent loads pipeline fine (R10); in-kernel per-batch barrier +10us (R12);
// plain cached loads == coherent loads for post-flag wu reads (R13).
// R14 = R13 + finalize tuned: 256 blocks (all CUs busy, was 128 = half idle),
// float2/thread, e-loads issued BEFORE the partial reduce to hide L3 latency.

#define S_LEN 4096
#define HD    256
#define B_N   32
#define NBLK  2048   // 64 blocks per batch
#define RPB   64     // rows per block
#define MAGIC 0x5EED5EEDu

// ws: wu[256] @0 (1KB) | wuflags 8x(128B) @1024 (1KB)
//     part_e[2048] @2048 (8KB) | part_d[2048] @10240 (8KB) | e_b[131072] @18432 (512KB)

__global__ void __launch_bounds__(256)
score_kernel(const float* __restrict__ u, const float* __restrict__ v,
             const float* __restrict__ W, const float* __restrict__ vp,
             float* __restrict__ wu, unsigned* __restrict__ wuflags,
             float* __restrict__ e_b,
             float* __restrict__ part_e, float* __restrict__ part_d)
{
    const int t    = threadIdx.x;
    const int wid  = t >> 6;
    const int lane = t & 63;
    const int g    = lane >> 4;
    const int sub  = lane & 15;
    const int b    = blockIdx.x >> 6;          // 64 blocks per batch
    const int row0 = blockIdx.x * RPB;
    const int off0 = sub * 4;

    __shared__ float red8[8][32];

    // ---- producers: blocks 0..7 compute wu slice h in [bid*32, bid*32+32) ----
    if (blockIdx.x < 8) {
        const int hh = t & 31;
        const int kk = t >> 5;
        const int h  = blockIdx.x * 32 + hh;
        float p = 0.f;
#pragma unroll 8
        for (int k = kk * 32; k < kk * 32 + 32; ++k)
            p = fmaf(vp[k], W[k * (2 * HD) + h], p);   // Wu[k,h]
        red8[kk][hh] = p;
        __syncthreads();
        if (kk == 0) {
            float a = 0.f;
#pragma unroll
            for (int j = 0; j < 8; ++j) a += red8[j][hh];
            wu[h] = a;                                  // plain store
        }
        __syncthreads();                                // stores issued+waited
        if (t == 0)                                     // release: writeback (8 total)
            __hip_atomic_store(&wuflags[blockIdx.x * 32], MAGIC,
                               __ATOMIC_RELEASE, __HIP_MEMORY_SCOPE_AGENT);
    }

    // ---- prefetch independent data while (possibly) waiting ----
    float4 v4[4];
#pragma unroll
    for (int i = 0; i < 4; ++i)
        v4[i] = *reinterpret_cast<const float4*>(v + b * HD + i * 64 + off0);
    const int sl0 = wid * 16 + g;                       // shot-0 local row
    const size_t ub0 = (size_t)(row0 + sl0) * HD;
    float4 u0[4];
#pragma unroll
    for (int i = 0; i < 4; ++i)
        u0[i] = *reinterpret_cast<const float4*>(u + ub0 + i * 64 + off0);

    // ---- wait for all 8 wu slices (relaxed coherent polls, no fence) ----
    if (t == 0) {
        for (;;) {
            unsigned ok = 0;
#pragma unroll
            for (int i = 0; i < 8; ++i)
                ok += (__hip_atomic_load(&wuflags[i * 32], __ATOMIC_RELAXED,
                                         __HIP_MEMORY_SCOPE_AGENT) == MAGIC);
            if (ok == 8) break;
            __builtin_amdgcn_s_sleep(8);
        }
    }
    __syncthreads();

    // ---- read wu with plain cached loads (fresh via L3; R13-validated) ----
    float4 w4[4];
#pragma unroll
    for (int i = 0; i < 4; ++i)
        w4[i] = *reinterpret_cast<const float4*>(wu + i * 64 + off0);

    float acc_e = 0.f, acc_d = 0.f;
#pragma unroll
    for (int shot = 0; shot < 4; ++shot) {
        const int sl = wid * 16 + shot * 4 + g;          // block-local row 0..63
        const size_t ubase = (size_t)(row0 + sl) * HD;
        float sc = 0.f, dd = 0.f;
#pragma unroll
        for (int i = 0; i < 4; ++i) {
            const float4 u4 = (shot == 0) ? u0[i]
                : *reinterpret_cast<const float4*>(u + ubase + i * 64 + off0);
            sc = fmaf(u4.x, w4[i].x, fmaf(u4.y, w4[i].y, fmaf(u4.z, w4[i].z, fmaf(u4.w, w4[i].w, sc))));
            const float dx = u4.x - v4[i].x, dy = u4.y - v4[i].y,
                        dz = u4.z - v4[i].z, dw = u4.w - v4[i].w;
            dd = fmaf(dx, dx, fmaf(dy, dy, fmaf(dz, dz, fmaf(dw, dw, dd))));
        }
#pragma unroll
        for (int m = 1; m < 16; m <<= 1) {
            sc += __shfl_xor(sc, m);
            dd += __shfl_xor(dd, m);
        }
        const float e = __expf(sc);
        if (sub == 0) e_b[row0 + sl] = e;
        acc_e += e;
        acc_d += e * sqrtf(dd);
    }
#pragma unroll
    for (int m = 16; m < 64; m <<= 1) {
        acc_e += __shfl_xor(acc_e, m);
        acc_d += __shfl_xor(acc_d, m);
    }

    __shared__ float redw[8];
    if (lane == 0) { redw[wid] = acc_e; redw[4 + wid] = acc_d; }
    __syncthreads();
    if (t == 0)       part_e[blockIdx.x] = redw[0] + redw[1] + redw[2] + redw[3];
    else if (t == 64) part_d[blockIdx.x] = redw[4] + redw[5] + redw[6] + redw[7];
}

// 256 blocks x 256 threads (all CUs). b = bid>>3, eighth q = bid&7, float2/thread.
// e-loads issued before the partial reduce so their latency hides under it.
__global__ void __launch_bounds__(256)
finalize_kernel(const float* __restrict__ e_in,
                const float* __restrict__ part_e, const float* __restrict__ part_d,
                float* __restrict__ w_d, float* __restrict__ attn) {
    const int t    = threadIdx.x;
    const int b    = blockIdx.x >> 3;
    const int q    = blockIdx.x & 7;
    const int lane = t & 63;

    const int i0 = b * S_LEN + q * 512 + t * 2;
    const float2 e2 = *reinterpret_cast<const float2*>(e_in + i0);   // issue early

    float pe = part_e[(b << 6) + lane];
    float pd = part_d[(b << 6) + lane];
#pragma unroll
    for (int m = 1; m < 64; m <<= 1) {
        pe += __shfl_xor(pe, m);
        pd += __shfl_xor(pd, m);
    }
    const float inv = 1.f / pe;
    if (q == 0 && t == 0) w_d[b] = pd * inv;

    float2 a2;
    a2.x = e2.x * inv; a2.y = e2.y * inv;
    *reinterpret_cast<float2*>(attn + i0) = a2;
}

extern "C" void kernel_launch(void* const* d_in, const int* in_sizes, int n_in,
                              void* d_out, int out_size, void* d_ws, size_t ws_size,
                              hipStream_t stream) {
    const float* u  = (const float*)d_in[0];   // (32, 4096, 256)
    const float* v  = (const float*)d_in[1];   // (32, 256)
    const float* W  = (const float*)d_in[2];   // (256, 512)
    // d_in[3] = b_attn: cancels in softmax, unused.
    const float* vp = (const float*)d_in[4];   // (256,)

    float* out  = (float*)d_out;
    float* w_d  = out;          // 32 floats
    float* attn = out + B_N;    // 32*4096 floats

    char*     ws      = (char*)d_ws;
    float*    wu      = (float*)ws;               // 256 f32
    unsigned* wuflags = (unsigned*)(ws + 1024);   // 8 flags, 128B apart
    float*    part_e  = (float*)(ws + 2048);      // 2048 f32
    float*    part_d  = (float*)(ws + 10240);     // 2048 f32
    float*    e_b     = (float*)(ws + 18432);     // 131072 f32

    score_kernel<<<NBLK, 256, 0, stream>>>(u, v, W, vp, wu, wuflags, e_b, part_e, part_d);
    finalize_kernel<<<256, 256, 0, stream>>>(e_b, part_e, part_d, w_d, attn);
}